// Round 6
// baseline (216.038 us; speedup 1.0000x reference)
//
#include <hip/hip_runtime.h>
#include <hip/hip_bf16.h>

// Problem dims (fixed by reference)
#define NS 256   // n_samples
#define NC 32    // n_channels (== K of the matvec)
#define NL 64    // lookback
#define NA 512   // n_assets
#define NH 32    // hidden

typedef float  f32x4  __attribute__((ext_vector_type(4)));
typedef __bf16 bf16x8 __attribute__((ext_vector_type(8)));

// tanh(x) = (e^{2x}-1)/(e^{2x}+1), via hw exp2/rcp. Clamp keeps t finite.
__device__ __forceinline__ float fast_tanh(float x) {
    float xc = fminf(fmaxf(x, -9.0f), 9.0f);
    float t = __builtin_amdgcn_exp2f(xc * 2.885390081777927f); // 2*log2(e)
    return (t - 1.0f) * __builtin_amdgcn_rcpf(t + 1.0f);
}

// async global->LDS, 16B per lane, lane i writes ldst + i*16 (linear dest)
#define GLOAD16(gsrc, ldst) \
  __builtin_amdgcn_global_load_lds((const __attribute__((address_space(1))) void*)(gsrc), \
                                   (__attribute__((address_space(3))) void*)(ldst), 16, 0, 0)

// out[s,h,a] = (1/64) * sum_l tanh( sum_c x[s,c,l,a]*W[h,c] + bias[h] )
// R6 = R5 (block = one full sample, 2KB-contiguous row reads, ring-2 128KiB,
// counted vmcnt, both-sides XOR bank swizzle) with ONE change:
//   512 threads = 8 waves = 2 waves/SIMD (was 4 waves = 1/SIMD), so the
//   iteration-boundary vmcnt+barrier drain of one wave hides under the
//   other wave's compute. Per-wave work halves (a-slice 64, 4 c-rows staged).
__global__ __launch_bounds__(512, 1) void tcrnn_kernel(
    const float* __restrict__ x,
    const float* __restrict__ Wih,
    const float* __restrict__ bih,
    const float* __restrict__ bhh,
    float* __restrict__ out)
{
    extern __shared__ float lds[];       // [2][NC][512] = 128 KiB

    const int tid  = threadIdx.x;
    const int lane = tid & 63;
    const int w    = tid >> 6;           // wave 0..7
    const int s    = blockIdx.x;         // one sample per block

    const int n = lane & 15;             // a within MFMA tile / h-row for A
    const int g = lane >> 4;             // k-group 0..3 (c = g*8 + j)

    // ---- A fragments: W[h][c], h = t*16 + n, k = g*8 + j ----
    bf16x8 Af[2];
    #pragma unroll
    for (int t = 0; t < 2; ++t) {
        const int h = t * 16 + n;
        const float4 w0 = *reinterpret_cast<const float4*>(Wih + h * NC + g * 8);
        const float4 w1 = *reinterpret_cast<const float4*>(Wih + h * NC + g * 8 + 4);
        Af[t][0] = (__bf16)w0.x; Af[t][1] = (__bf16)w0.y;
        Af[t][2] = (__bf16)w0.z; Af[t][3] = (__bf16)w0.w;
        Af[t][4] = (__bf16)w1.x; Af[t][5] = (__bf16)w1.y;
        Af[t][6] = (__bf16)w1.z; Af[t][7] = (__bf16)w1.w;
    }

    // ---- per-lane output bias: h_out = t*16 + g*4 + r ----
    float bias[8];
    #pragma unroll
    for (int t = 0; t < 2; ++t)
        #pragma unroll
        for (int r = 0; r < 4; ++r) {
            const int h = t * 16 + g * 4 + r;
            bias[t * 4 + r] = bih[h] + bhh[h];
        }

    // ---- staging: wave w owns c-rows 4w..4w+3; 2KB contiguous per row ----
    // Store-side swizzle keyed on c>>3 (so the reader's g-keyed inverse
    // stays valid): Xw = ((c>>3)&1)<<4 = ((w>>1)&1)<<4 for rows 4w..4w+3.
    const int Xw = ((w >> 1) & 1) << 4;
    const int lane_off = (lane * 4) ^ Xw;        // float offset within half
    const float* xw = x + (size_t)(s * NC + w * 4) * (NL * NA) + lane_off;

    auto stage = [&](int l, int buf) {           // 8 gloads: 4 rows x 2KB
        #pragma unroll
        for (int i = 0; i < 4; ++i) {
            const float* gsrc = xw + ((size_t)i * NL + l) * NA;
            float* ldst = lds + (((size_t)buf * NC + w * 4 + i) << 9);
            GLOAD16(gsrc, ldst);                 // a 0..255   (swizzled)
            GLOAD16(gsrc + 256, ldst + 256);     // a 256..511 (swizzled)
        }
    };

    f32x4 acc[4][2];
    #pragma unroll
    for (int t2 = 0; t2 < 4; ++t2) {
        acc[t2][0] = (f32x4){0.f, 0.f, 0.f, 0.f};
        acc[t2][1] = (f32x4){0.f, 0.f, 0.f, 0.f};
    }
    const f32x4 z = {0.f, 0.f, 0.f, 0.f};
    const int Xg = (g & 1) << 4;                 // reader-side inverse swizzle

    stage(0, 0);
    for (int l = 0; l < NL; ++l) {
        // barrier #1: all waves done computing l-1 -> buf[(l+1)&1] reusable.
        if (l > 0) asm volatile("s_barrier" ::: "memory");

        if (l + 1 < NL) {
            stage(l + 1, (l + 1) & 1);                       // 8 gloads
            asm volatile("s_waitcnt vmcnt(8)" ::: "memory"); // stage(l) done
        } else {
            asm volatile("s_waitcnt vmcnt(0)" ::: "memory");
        }
        asm volatile("s_barrier" ::: "memory");   // stage(l) visible to all

        // wave w computes a-slice [w*64, w*64+64)
        #pragma unroll
        for (int t2 = 0; t2 < 4; ++t2) {
            const int A    = w * 64 + t2 * 16 + n;            // global a
            const int half = A >> 8;                          // 0 or 1
            const int sa   = half * 256 + ((A & 255) ^ Xg);   // swizzled pos
            const float* base = lds + (((size_t)(l & 1) * NC + g * 8) << 9) + sa;
            bf16x8 B;
            #pragma unroll
            for (int j = 0; j < 8; ++j)
                B[j] = (__bf16)base[j * 512];     // 2-way banks (free)

            f32x4 pre0 = __builtin_amdgcn_mfma_f32_16x16x32_bf16(Af[0], B, z, 0, 0, 0);
            f32x4 pre1 = __builtin_amdgcn_mfma_f32_16x16x32_bf16(Af[1], B, z, 0, 0, 0);

            #pragma unroll
            for (int r4 = 0; r4 < 4; ++r4) {
                acc[t2][0][r4] += fast_tanh(pre0[r4] + bias[r4]);
                acc[t2][1][r4] += fast_tanh(pre1[r4] + bias[4 + r4]);
            }
        }
    }

    // ---- store: D col = n (=a), row = g*4 + r (+16 for tile 1) ----
    #pragma unroll
    for (int t2 = 0; t2 < 4; ++t2) {
        const int a = w * 64 + t2 * 16 + n;
        float* op = out + (size_t)s * (NH * NA) + a;
        #pragma unroll
        for (int r4 = 0; r4 < 4; ++r4) {
            op[(size_t)(g * 4 + r4) * NA]      = acc[t2][0][r4] * 0.015625f;
            op[(size_t)(16 + g * 4 + r4) * NA] = acc[t2][1][r4] * 0.015625f;
        }
    }
}

extern "C" void kernel_launch(void* const* d_in, const int* in_sizes, int n_in,
                              void* d_out, int out_size, void* d_ws, size_t ws_size,
                              hipStream_t stream) {
    const float* x    = (const float*)d_in[0];
    const float* Wih  = (const float*)d_in[1];
    // d_in[2] = W_hh: mathematically dead (hx == 0 every step)
    const float* bih  = (const float*)d_in[3];
    const float* bhh  = (const float*)d_in[4];
    float* out = (float*)d_out;

    // 128 KiB dynamic LDS needs explicit opt-in (gfx950 has 160 KiB/CU).
    (void)hipFuncSetAttribute((const void*)tcrnn_kernel,
                              hipFuncAttributeMaxDynamicSharedMemorySize,
                              2 * NC * NA * (int)sizeof(float));

    dim3 grid(NS);      // one block per sample, 1 block/CU
    dim3 block(512);    // 8 waves = 2 waves/SIMD
    tcrnn_kernel<<<grid, block, 2 * NC * NA * sizeof(float), stream>>>(
        x, Wih, bih, bhh, out);
}

// Round 7
// 198.152 us; speedup vs baseline: 1.0903x; 1.0903x over previous
//
#include <hip/hip_runtime.h>
#include <hip/hip_bf16.h>

// Problem dims (fixed by reference)
#define NS 256   // n_samples
#define NC 32    // n_channels (== K of the matvec)
#define NL 64    // lookback
#define NA 512   // n_assets
#define NH 32    // hidden

typedef float  f32x4  __attribute__((ext_vector_type(4)));
typedef __bf16 bf16x8 __attribute__((ext_vector_type(8)));

// tanh(x) = (e^{2x}-1)/(e^{2x}+1), via hw exp2/rcp. Clamp keeps t finite.
__device__ __forceinline__ float fast_tanh(float x) {
    float xc = fminf(fmaxf(x, -9.0f), 9.0f);
    float t = __builtin_amdgcn_exp2f(xc * 2.885390081777927f); // 2*log2(e)
    return (t - 1.0f) * __builtin_amdgcn_rcpf(t + 1.0f);
}

// async global->LDS, 16B per lane, lane i writes ldst + i*16 (linear dest)
#define GLOAD16(gsrc, ldst) \
  __builtin_amdgcn_global_load_lds((const __attribute__((address_space(1))) void*)(gsrc), \
                                   (__attribute__((address_space(3))) void*)(ldst), 16, 0, 0)

// out[s,h,a] = (1/64) * sum_l tanh( sum_c x[s,c,l,a]*W[h,c] + bias[h] )
// R7 = R5 (block = full sample, 4 waves, 2KB-contiguous row visits,
// ring-2 128KiB, both-sides XOR bank swizzle) with ONE schedule change:
//  * single barrier per iteration (stage(l+1) now issues AFTER the
//    visibility barrier, so the old "buffer reusable" barrier is redundant);
//  * stage issue de-bursted: 4 gloads interleaved into each of the first 4
//    compute tiles -> load issue spread over the compute phase (T14), memory
//    controller sees a smooth request stream instead of 64KB bursts.
__global__ __launch_bounds__(256, 1) void tcrnn_kernel(
    const float* __restrict__ x,
    const float* __restrict__ Wih,
    const float* __restrict__ bih,
    const float* __restrict__ bhh,
    float* __restrict__ out)
{
    extern __shared__ float lds[];       // [2][NC][512] = 128 KiB

    const int tid  = threadIdx.x;
    const int lane = tid & 63;
    const int w    = tid >> 6;           // wave 0..3
    const int s    = blockIdx.x;         // one sample per block

    const int n = lane & 15;             // a within MFMA tile / h-row for A
    const int g = lane >> 4;             // k-group 0..3 (c = g*8 + j)

    // ---- A fragments: W[h][c], h = t*16 + n, k = g*8 + j ----
    bf16x8 Af[2];
    #pragma unroll
    for (int t = 0; t < 2; ++t) {
        const int h = t * 16 + n;
        const float4 w0 = *reinterpret_cast<const float4*>(Wih + h * NC + g * 8);
        const float4 w1 = *reinterpret_cast<const float4*>(Wih + h * NC + g * 8 + 4);
        Af[t][0] = (__bf16)w0.x; Af[t][1] = (__bf16)w0.y;
        Af[t][2] = (__bf16)w0.z; Af[t][3] = (__bf16)w0.w;
        Af[t][4] = (__bf16)w1.x; Af[t][5] = (__bf16)w1.y;
        Af[t][6] = (__bf16)w1.z; Af[t][7] = (__bf16)w1.w;
    }

    // ---- per-lane output bias: h_out = t*16 + g*4 + r ----
    float bias[8];
    #pragma unroll
    for (int t = 0; t < 2; ++t)
        #pragma unroll
        for (int r = 0; r < 4; ++r) {
            const int h = t * 16 + g * 4 + r;
            bias[t * 4 + r] = bih[h] + bhh[h];
        }

    // ---- staging: wave w owns c-rows 8w..8w+7; 2KB contiguous per row ----
    // LDS dest linear (base + lane*16B); source lane offset pre-swizzled by
    // Xw (bit4 = 64B blocks) so stored a' = a ^ Xw_row within each 256-half.
    const int Xw = (w & 1) << 4;
    const int lane_off = (lane * 4) ^ Xw;        // float offset within half
    const float* xw = x + (size_t)(s * NC + w * 8) * (NL * NA) + lane_off;

    // issue 2 rows (4 gloads) of plane l into ring buffer `buf`
    auto stage2 = [&](int l, int buf, int i0) {
        #pragma unroll
        for (int i = i0; i < i0 + 2; ++i) {
            const float* gsrc = xw + ((size_t)i * NL + l) * NA;
            float* ldst = lds + (((size_t)buf * NC + w * 8 + i) << 9);
            GLOAD16(gsrc, ldst);                 // a 0..255   (swizzled)
            GLOAD16(gsrc + 256, ldst + 256);     // a 256..511 (swizzled)
        }
    };

    f32x4 acc[8][2];
    #pragma unroll
    for (int t2 = 0; t2 < 8; ++t2) {
        acc[t2][0] = (f32x4){0.f, 0.f, 0.f, 0.f};
        acc[t2][1] = (f32x4){0.f, 0.f, 0.f, 0.f};
    }
    const f32x4 z = {0.f, 0.f, 0.f, 0.f};
    const int Xg = (g & 1) << 4;                 // reader-side inverse swizzle

    // prologue: stage plane 0 (burst, one-time HBM latency hit)
    stage2(0, 0, 0); stage2(0, 0, 2); stage2(0, 0, 4); stage2(0, 0, 6);

    for (int l = 0; l < NL; ++l) {
        // stage(l) complete (own loads), then make it visible to all waves.
        asm volatile("s_waitcnt vmcnt(0)" ::: "memory");
        asm volatile("s_barrier" ::: "memory");

        // wave w computes a-slice [w*128, w*128+128); stage(l+1) interleaved
        // into the first 4 tiles (4 gloads each) -> de-bursted issue, and the
        // last load has >=4 tiles of compute to cover HBM latency.
        #pragma unroll
        for (int t2 = 0; t2 < 8; ++t2) {
            if (t2 < 4 && l + 1 < NL)
                stage2(l + 1, (l + 1) & 1, 2 * t2);

            const int A    = w * 128 + t2 * 16 + n;           // global a
            const int half = A >> 8;                          // 0 or 1
            const int sa   = half * 256 + ((A & 255) ^ Xg);   // swizzled pos
            const float* base = lds + (((size_t)(l & 1) * NC + g * 8) << 9) + sa;
            bf16x8 B;
            #pragma unroll
            for (int j = 0; j < 8; ++j)
                B[j] = (__bf16)base[j * 512];     // 2-way banks (free)

            f32x4 pre0 = __builtin_amdgcn_mfma_f32_16x16x32_bf16(Af[0], B, z, 0, 0, 0);
            f32x4 pre1 = __builtin_amdgcn_mfma_f32_16x16x32_bf16(Af[1], B, z, 0, 0, 0);

            #pragma unroll
            for (int r4 = 0; r4 < 4; ++r4) {
                acc[t2][0][r4] += fast_tanh(pre0[r4] + bias[r4]);
                acc[t2][1][r4] += fast_tanh(pre1[r4] + bias[4 + r4]);
            }
        }
    }

    // ---- store: D col = n (=a), row = g*4 + r (+16 for tile 1) ----
    #pragma unroll
    for (int t2 = 0; t2 < 8; ++t2) {
        const int a = w * 128 + t2 * 16 + n;
        float* op = out + (size_t)s * (NH * NA) + a;
        #pragma unroll
        for (int r4 = 0; r4 < 4; ++r4) {
            op[(size_t)(g * 4 + r4) * NA]      = acc[t2][0][r4] * 0.015625f;
            op[(size_t)(16 + g * 4 + r4) * NA] = acc[t2][1][r4] * 0.015625f;
        }
    }
}

extern "C" void kernel_launch(void* const* d_in, const int* in_sizes, int n_in,
                              void* d_out, int out_size, void* d_ws, size_t ws_size,
                              hipStream_t stream) {
    const float* x    = (const float*)d_in[0];
    const float* Wih  = (const float*)d_in[1];
    // d_in[2] = W_hh: mathematically dead (hx == 0 every step)
    const float* bih  = (const float*)d_in[3];
    const float* bhh  = (const float*)d_in[4];
    float* out = (float*)d_out;

    // 128 KiB dynamic LDS needs explicit opt-in (gfx950 has 160 KiB/CU).
    (void)hipFuncSetAttribute((const void*)tcrnn_kernel,
                              hipFuncAttributeMaxDynamicSharedMemorySize,
                              2 * NC * NA * (int)sizeof(float));

    dim3 grid(NS);      // one block per sample, 1 block/CU
    dim3 block(256);    // 4 waves = 1 wave/SIMD
    tcrnn_kernel<<<grid, block, 2 * NC * NA * sizeof(float), stream>>>(
        x, Wih, bih, bhh, out);
}

// Round 8
// 187.434 us; speedup vs baseline: 1.1526x; 1.0572x over previous
//
#include <hip/hip_runtime.h>
#include <hip/hip_bf16.h>

// Problem dims (fixed by reference)
#define NS 256   // n_samples
#define NC 32    // n_channels (== K of the matvec)
#define NL 64    // lookback
#define NA 512   // n_assets
#define NH 32    // hidden

typedef float  f32x4  __attribute__((ext_vector_type(4)));
typedef __bf16 bf16x8 __attribute__((ext_vector_type(8)));

// tanh(x) = (e^{2x}-1)/(e^{2x}+1), via hw exp2/rcp. Clamp keeps t finite.
__device__ __forceinline__ float fast_tanh(float x) {
    float xc = fminf(fmaxf(x, -9.0f), 9.0f);
    float t = __builtin_amdgcn_exp2f(xc * 2.885390081777927f); // 2*log2(e)
    return (t - 1.0f) * __builtin_amdgcn_rcpf(t + 1.0f);
}

// async global->LDS, 16B per lane, lane i writes ldst + i*16 (linear dest)
#define GLOAD16(gsrc, ldst) \
  __builtin_amdgcn_global_load_lds((const __attribute__((address_space(1))) void*)(gsrc), \
                                   (__attribute__((address_space(3))) void*)(ldst), 16, 0, 0)

// out[s,h,a] = (1/64) * sum_l tanh( sum_c x[s,c,l,a]*W[h,c] + bias[h] )
// FINAL (= R5, the measured best at 186.9 us / 5.84 TB/s = 93% of the
// 6.29 TB/s copy ceiling). Structure and why each piece is there:
//  * block = ONE full sample (grid 256 = 1 block/CU): each (s,c,l) HBM visit
//    is a full 2KB contiguous row and concurrent stream count is minimized
//    (8192); this was the +12% lever (R4->R5). Wider visits would need
//    >160KiB LDS; narrower (R1-R4) measured slower.
//  * ring-2 of full l-planes [2][32][512]f32 = 128 KiB dynamic LDS.
//  * two barriers/iter + counted vmcnt(16): stage(l+1) issues BEFORE the
//    wait, wait covers only the 16 older loads -> 16 loads stay in flight
//    across the barrier. Single-barrier/full-drain (R7) and 2 waves/SIMD
//    (R6) both measured SLOWER (de-pipelining / barrier-width effects).
//  * both-sides XOR bank swizzle (bit4 keyed on c>>3): ds_read 2-way = free.
//  * bf16 MFMA 16x16x32 (K = all 32 channels in one instruction); W_hh is
//    mathematically dead (hx==0 every step). absmax 1.95e-3 << 9.4e-3.
__global__ __launch_bounds__(256, 1) void tcrnn_kernel(
    const float* __restrict__ x,
    const float* __restrict__ Wih,
    const float* __restrict__ bih,
    const float* __restrict__ bhh,
    float* __restrict__ out)
{
    extern __shared__ float lds[];       // [2][NC][512] = 128 KiB

    const int tid  = threadIdx.x;
    const int lane = tid & 63;
    const int w    = tid >> 6;           // wave 0..3
    const int s    = blockIdx.x;         // one sample per block

    const int n = lane & 15;             // a within MFMA tile / h-row for A
    const int g = lane >> 4;             // k-group 0..3 (c = g*8 + j)

    // ---- A fragments: W[h][c], h = t*16 + n, k = g*8 + j ----
    bf16x8 Af[2];
    #pragma unroll
    for (int t = 0; t < 2; ++t) {
        const int h = t * 16 + n;
        const float4 w0 = *reinterpret_cast<const float4*>(Wih + h * NC + g * 8);
        const float4 w1 = *reinterpret_cast<const float4*>(Wih + h * NC + g * 8 + 4);
        Af[t][0] = (__bf16)w0.x; Af[t][1] = (__bf16)w0.y;
        Af[t][2] = (__bf16)w0.z; Af[t][3] = (__bf16)w0.w;
        Af[t][4] = (__bf16)w1.x; Af[t][5] = (__bf16)w1.y;
        Af[t][6] = (__bf16)w1.z; Af[t][7] = (__bf16)w1.w;
    }

    // ---- per-lane output bias: h_out = t*16 + g*4 + r ----
    float bias[8];
    #pragma unroll
    for (int t = 0; t < 2; ++t)
        #pragma unroll
        for (int r = 0; r < 4; ++r) {
            const int h = t * 16 + g * 4 + r;
            bias[t * 4 + r] = bih[h] + bhh[h];
        }

    // ---- staging: wave w owns c-rows 8w..8w+7; 2KB contiguous per row ----
    // LDS dest linear (base + lane*16B); source lane offset pre-swizzled by
    // Xw (bit4 = 64B blocks) so stored a' = a ^ Xw_row within each 256-half.
    const int Xw = (w & 1) << 4;
    const int lane_off = (lane * 4) ^ Xw;        // float offset within half
    const float* xw = x + (size_t)(s * NC + w * 8) * (NL * NA) + lane_off;

    auto stage = [&](int l, int buf) {           // 16 gloads: 8 rows x 2KB
        #pragma unroll
        for (int i = 0; i < 8; ++i) {
            const float* gsrc = xw + ((size_t)i * NL + l) * NA;
            float* ldst = lds + (((size_t)buf * NC + w * 8 + i) << 9);
            GLOAD16(gsrc, ldst);                 // a 0..255   (swizzled)
            GLOAD16(gsrc + 256, ldst + 256);     // a 256..511 (swizzled)
        }
    };

    f32x4 acc[8][2];
    #pragma unroll
    for (int t2 = 0; t2 < 8; ++t2) {
        acc[t2][0] = (f32x4){0.f, 0.f, 0.f, 0.f};
        acc[t2][1] = (f32x4){0.f, 0.f, 0.f, 0.f};
    }
    const f32x4 z = {0.f, 0.f, 0.f, 0.f};
    const int Xg = (g & 1) << 4;                 // reader-side inverse swizzle

    stage(0, 0);
    for (int l = 0; l < NL; ++l) {
        // barrier #1: all waves done computing l-1 -> buf[(l+1)&1] reusable.
        if (l > 0) asm volatile("s_barrier" ::: "memory");

        if (l + 1 < NL) {
            stage(l + 1, (l + 1) & 1);                        // 16 gloads
            asm volatile("s_waitcnt vmcnt(16)" ::: "memory"); // stage(l) done
        } else {
            asm volatile("s_waitcnt vmcnt(0)" ::: "memory");
        }
        asm volatile("s_barrier" ::: "memory");   // stage(l) visible to all

        // wave w computes a-slice [w*128, w*128+128)
        #pragma unroll
        for (int t2 = 0; t2 < 8; ++t2) {
            const int A    = w * 128 + t2 * 16 + n;          // global a
            const int half = A >> 8;                          // 0 or 1
            const int sa   = half * 256 + ((A & 255) ^ Xg);   // swizzled pos
            const float* base = lds + (((size_t)(l & 1) * NC + g * 8) << 9) + sa;
            bf16x8 B;
            #pragma unroll
            for (int j = 0; j < 8; ++j)
                B[j] = (__bf16)base[j * 512];     // 2-way banks (free)

            f32x4 pre0 = __builtin_amdgcn_mfma_f32_16x16x32_bf16(Af[0], B, z, 0, 0, 0);
            f32x4 pre1 = __builtin_amdgcn_mfma_f32_16x16x32_bf16(Af[1], B, z, 0, 0, 0);

            #pragma unroll
            for (int r4 = 0; r4 < 4; ++r4) {
                acc[t2][0][r4] += fast_tanh(pre0[r4] + bias[r4]);
                acc[t2][1][r4] += fast_tanh(pre1[r4] + bias[4 + r4]);
            }
        }
    }

    // ---- store: D col = n (=a), row = g*4 + r (+16 for tile 1) ----
    #pragma unroll
    for (int t2 = 0; t2 < 8; ++t2) {
        const int a = w * 128 + t2 * 16 + n;
        float* op = out + (size_t)s * (NH * NA) + a;
        #pragma unroll
        for (int r4 = 0; r4 < 4; ++r4) {
            op[(size_t)(g * 4 + r4) * NA]      = acc[t2][0][r4] * 0.015625f;
            op[(size_t)(16 + g * 4 + r4) * NA] = acc[t2][1][r4] * 0.015625f;
        }
    }
}

extern "C" void kernel_launch(void* const* d_in, const int* in_sizes, int n_in,
                              void* d_out, int out_size, void* d_ws, size_t ws_size,
                              hipStream_t stream) {
    const float* x    = (const float*)d_in[0];
    const float* Wih  = (const float*)d_in[1];
    // d_in[2] = W_hh: mathematically dead (hx == 0 every step)
    const float* bih  = (const float*)d_in[3];
    const float* bhh  = (const float*)d_in[4];
    float* out = (float*)d_out;

    // 128 KiB dynamic LDS needs explicit opt-in (gfx950 has 160 KiB/CU).
    (void)hipFuncSetAttribute((const void*)tcrnn_kernel,
                              hipFuncAttributeMaxDynamicSharedMemorySize,
                              2 * NC * NA * (int)sizeof(float));

    dim3 grid(NS);      // one block per sample, 1 block/CU
    dim3 block(256);    // 4 waves = 1 wave/SIMD
    tcrnn_kernel<<<grid, block, 2 * NC * NA * sizeof(float), stream>>>(
        x, Wih, bih, bhh, out);
}